// Round 1
// baseline (774.219 us; speedup 1.0000x reference)
//
#include <hip/hip_runtime.h>
#include <cstdint>

#define NTOK 4096
#define DDIM 1024
#define HDIM 4096
#define ODIM 1024
#define NEXP 8
#define NSLOT (2*NTOK)
#define MAXT128 72
#define MAXT256 40

typedef __bf16 bf16x8 __attribute__((ext_vector_type(8)));
typedef float  f32x4  __attribute__((ext_vector_type(4)));
typedef unsigned short ushort8v __attribute__((ext_vector_type(8)));

__device__ __forceinline__ unsigned short f2bf(float f) {
    union { float f; unsigned int u; } v; v.f = f;
    unsigned int r = (v.u + 0x7FFF + ((v.u >> 16) & 1)) >> 16;
    return (unsigned short)r;
}

typedef const void __attribute__((address_space(1)))* gas_ptr;
typedef void       __attribute__((address_space(3)))* las_ptr;

// ---- gate: logits = relu(x@Wg), top-2 (lowest-index tie-break), fused x->bf16 cast ----
__global__ void gate_kernel(const float* __restrict__ x, const float* __restrict__ Wg,
                            int2* __restrict__ sel, float2* __restrict__ wts,
                            int* __restrict__ counts, unsigned short* __restrict__ xb) {
    int wave = threadIdx.x >> 6;
    int lane = threadIdx.x & 63;
    int n = blockIdx.x * 4 + wave;
    float acc[NEXP];
#pragma unroll
    for (int e = 0; e < NEXP; e++) acc[e] = 0.f;
    const float* xr = x + (size_t)n * DDIM;
    unsigned short* xbr = xb + (size_t)n * DDIM;
#pragma unroll
    for (int i = 0; i < 4; i++) {
        int d = i * 256 + lane * 4;
        float4 xv = *(const float4*)&xr[d];
        ushort4 o;
        o.x = f2bf(xv.x); o.y = f2bf(xv.y); o.z = f2bf(xv.z); o.w = f2bf(xv.w);
        *(ushort4*)&xbr[d] = o;
        const float* wr = Wg + (size_t)d * NEXP;
#pragma unroll
        for (int jj = 0; jj < 4; jj++) {
            float xs = (jj == 0) ? xv.x : (jj == 1) ? xv.y : (jj == 2) ? xv.z : xv.w;
#pragma unroll
            for (int e = 0; e < NEXP; e++)
                acc[e] = fmaf(xs, wr[jj * NEXP + e], acc[e]);
        }
    }
#pragma unroll
    for (int e = 0; e < NEXP; e++) {
#pragma unroll
        for (int off = 32; off >= 1; off >>= 1)
            acc[e] += __shfl_xor(acc[e], off, 64);
    }
    if (lane == 0) {
        float l0 = -1e30f, l1 = -1e30f; int e0 = 0, e1 = 0;
#pragma unroll
        for (int e = 0; e < NEXP; e++) {
            float v = fmaxf(acc[e], 0.f);     // relu before softmax
            if (v > l0)      { l1 = l0; e1 = e0; l0 = v; e0 = e; }
            else if (v > l1) { l1 = v;  e1 = e; }
        }
        float w0 = 1.f / (1.f + expf(l1 - l0));   // softmax Z cancels in top-2 renorm
        sel[n] = make_int2(e0, e1);
        wts[n] = make_float2(w0, 1.f - w0);
        atomicAdd(&counts[e0], 1);
        atomicAdd(&counts[e1], 1);
    }
}

// ---- route: scan counts -> offsets + 128-tile and 256-tile tables, slot assignment ----
__global__ void route_kernel(const int2* __restrict__ sel, const float2* __restrict__ wts,
                             const int* __restrict__ counts, int* __restrict__ offsets,
                             int4* __restrict__ t128, int* __restrict__ nt128,
                             int4* __restrict__ t256, int* __restrict__ nt256,
                             int* __restrict__ slot_token, float* __restrict__ slot_weight) {
    __shared__ int cur[NEXP];
    int t = threadIdx.x;
    if (t == 0) {
        int s = 0, n1 = 0, n2 = 0;
        for (int e = 0; e < NEXP; e++) {
            offsets[e] = s; cur[e] = s;
            int c = counts[e];
            for (int r = 0; r < c; r += 128)
                t128[n1++] = make_int4(e, s + r, min(128, c - r), 0);
            for (int r = 0; r < c; r += 256)
                t256[n2++] = make_int4(e, s + r, min(256, c - r), 0);
            s += c;
        }
        offsets[NEXP] = s;
        *nt128 = n1; *nt256 = n2;
    }
    __syncthreads();
    for (int n = t; n < NTOK; n += blockDim.x) {
        int2 se = sel[n]; float2 w = wts[n];
        int p0 = atomicAdd(&cur[se.x], 1);
        slot_token[p0] = n; slot_weight[p0] = w.x;
        int p1 = atomicAdd(&cur[se.y], 1);
        slot_token[p1] = n; slot_weight[p1] = w.y;
    }
}

// ---- transpose+cast: src [R][C] fp32 -> dst [C][R] bf16, per expert (z) ----
__global__ void transpose_cast_kernel(const float* __restrict__ src, unsigned short* __restrict__ dst,
                                      int R, int C) {
    __shared__ float tile[64][65];
    int e = blockIdx.z;
    const float* s = src + (size_t)e * R * C;
    unsigned short* d = dst + (size_t)e * R * C;
    int t = threadIdx.x;                      // 256 threads
    int r0 = blockIdx.y * 64, c0 = blockIdx.x * 64;
#pragma unroll
    for (int p = 0; p < 4; p++) {
        int r = p * 16 + (t >> 4);
        int c = (t & 15) * 4;
        float4 v = *(const float4*)&s[(size_t)(r0 + r) * C + (c0 + c)];
        tile[r][c] = v.x; tile[r][c + 1] = v.y; tile[r][c + 2] = v.z; tile[r][c + 3] = v.w;
    }
    __syncthreads();
    int c = t >> 2, rb = (t & 3) * 16;
#pragma unroll
    for (int j = 0; j < 2; j++) {
        ushort8v v;
#pragma unroll
        for (int i = 0; i < 8; i++) v[i] = f2bf(tile[rb + j * 8 + i][c]);
        *(ushort8v*)&d[(size_t)(c0 + c) * R + (r0 + rb + j * 8)] = v;
    }
}

// ---- 8-phase 256x256 MFMA GEMM (T2 swizzle + T3/T4 counted vmcnt + T5 setprio) ----
// 512 threads = 8 waves (2M x 4N), per-wave C = 128x64 (8x4 frags), BK=64, LDS 128KB.
// Per K-tile: 4 quadrant phases; each phase stages one half-tile of tile t+1 into the
// buffer freed by tile t-1; vmcnt(2) only at the group boundary (never 0 in main loop).
// LDS swizzle: 16B unit slot = kgrp ^ (row&7); inverse folded into per-lane global addr.
// MODE 1: A gathered via slot_token; epi: +b1, relu, bf16 -> h
// MODE 2: A = h slots;               epi: +b2, relu, *wgt, atomicAdd out
template <int MODE, int KDIM, int NDIM>
__global__ __launch_bounds__(512, 2) void moe_gemm8_kernel(
    const unsigned short* __restrict__ A,
    const unsigned short* __restrict__ B,
    const float* __restrict__ bias,
    const int4* __restrict__ tile_meta,
    const int* __restrict__ ntiles,
    const int* __restrict__ slot_token,
    const float* __restrict__ slot_weight,
    unsigned short* __restrict__ h,
    float* __restrict__ out) {

    int tileIdx = blockIdx.y;
    int colBase = blockIdx.x * 256;
    if (tileIdx >= *ntiles) return;
    int4 tm = tile_meta[tileIdx];
    int e = tm.x, slotBase = tm.y, rows = tm.z;

    constexpr int NT = KDIM / 64;

    __shared__ __align__(16) unsigned short As[2][16384];   // [buf][256 rows x 64 k] 32KB each
    __shared__ __align__(16) unsigned short Bs[2][16384];

    int tid = threadIdx.x;
    int w = tid >> 6, lane = tid & 63;
    int quad = lane >> 4, lr = lane & 15;
    int wm = w >> 2, wn = w & 3;                 // 2 x 4 wave grid

    const unsigned short* Be = B + (size_t)e * NDIM * KDIM;

    // ---- staging addresses: unit u=(c*512+w*64+lane) covers (row=u>>3, slot=u&7);
    //      slot s holds global kgrp g = s ^ (row&7); w*8 & 7 == 0 so g is (h,c)-invariant
    int g = (lane & 7) ^ ((lane >> 3) & 7);
    unsigned int aoff[4], boff[4];               // element offsets, [h*2+c]
#pragma unroll
    for (int i = 0; i < 4; i++) {
        int hh = i >> 1, c = i & 1;
        int r = hh * 128 + c * 64 + w * 8 + (lane >> 3);
        int slot = min(slotBase + r, NSLOT - 1);
        if constexpr (MODE == 1) aoff[i] = (unsigned)(slot_token[slot] * KDIM + g * 8);
        else                     aoff[i] = (unsigned)(slot * KDIM + g * 8);
        boff[i] = (unsigned)((colBase + r) * KDIM + g * 8);
    }

    auto stage = [&](int t, int sb, int half, bool isA) {
        const unsigned short* base = isA ? A : Be;
        const unsigned int* off = isA ? aoff : boff;
        char* lb = (char*)(isA ? &As[sb][0] : &Bs[sb][0]) + half * 16384;
#pragma unroll
        for (int c = 0; c < 2; c++) {
            __builtin_amdgcn_global_load_lds(
                (gas_ptr)(base + off[half * 2 + c] + t * 64),
                (las_ptr)(lb + (c * 512 + w * 64) * 16), 16, 0, 0);
        }
    };

    auto ldA = [&](int b, int rbase, int kk) -> bf16x8 {
        int row = rbase + lr;
        int sl = (kk * 4 + quad) ^ (row & 7);
        return *(const bf16x8*)((const char*)&As[0][0] + b * 32768 + row * 128 + sl * 16);
    };
    auto ldB = [&](int b, int rbase, int kk) -> bf16x8 {
        int row = rbase + lr;
        int sl = (kk * 4 + quad) ^ (row & 7);
        return *(const bf16x8*)((const char*)&Bs[0][0] + b * 32768 + row * 128 + sl * 16);
    };

    f32x4 zero = {0.f, 0.f, 0.f, 0.f};
    f32x4 acc[8][4];
#pragma unroll
    for (int m = 0; m < 8; m++)
#pragma unroll
        for (int n = 0; n < 4; n++) acc[m][n] = zero;

    // prologue: stage tile 0 fully into buf0 (8 loads/thread)
    stage(0, 0, 0, true);  stage(0, 0, 1, true);
    stage(0, 0, 0, false); stage(0, 0, 1, false);

    for (int t = 0; t < NT; ++t) {
        const int b = t & 1, sb = b ^ 1;
        const bool st = (t + 1 < NT);
        const int ts = t + 1;
        bf16x8 afr[4][2], bf0[2][2], bf1[2][2];

        // ---------- phase 0: quadrant (0,0); stage A-half0(t+1); group-boundary wait
        if (st) stage(ts, sb, 0, true);
        if (st) asm volatile("s_waitcnt vmcnt(2)" ::: "memory");
        else    asm volatile("s_waitcnt vmcnt(0)" ::: "memory");
        __builtin_amdgcn_s_barrier();
#pragma unroll
        for (int mi = 0; mi < 4; mi++)
#pragma unroll
            for (int kk = 0; kk < 2; kk++)
                afr[mi][kk] = ldA(b, wm * 128 + mi * 16, kk);
#pragma unroll
        for (int ni = 0; ni < 2; ni++)
#pragma unroll
            for (int kk = 0; kk < 2; kk++)
                bf0[ni][kk] = ldB(b, wn * 64 + ni * 16, kk);
        asm volatile("s_waitcnt lgkmcnt(0)" ::: "memory");
        __builtin_amdgcn_s_setprio(1);
#pragma unroll
        for (int mi = 0; mi < 4; mi++)
#pragma unroll
            for (int ni = 0; ni < 2; ni++)
#pragma unroll
                for (int kk = 0; kk < 2; kk++)
                    acc[mi][ni] = __builtin_amdgcn_mfma_f32_16x16x32_bf16(
                        afr[mi][kk], bf0[ni][kk], acc[mi][ni], 0, 0, 0);
        __builtin_amdgcn_s_setprio(0);
        __builtin_amdgcn_s_barrier();

        // ---------- phase 1: quadrant (0,1); stage A-half1(t+1)
#pragma unroll
        for (int ni = 0; ni < 2; ni++)
#pragma unroll
            for (int kk = 0; kk < 2; kk++)
                bf1[ni][kk] = ldB(b, wn * 64 + 32 + ni * 16, kk);
        if (st) stage(ts, sb, 1, true);
        __builtin_amdgcn_s_barrier();
        asm volatile("s_waitcnt lgkmcnt(0)" ::: "memory");
        __builtin_amdgcn_s_setprio(1);
#pragma unroll
        for (int mi = 0; mi < 4; mi++)
#pragma unroll
            for (int ni = 0; ni < 2; ni++)
#pragma unroll
                for (int kk = 0; kk < 2; kk++)
                    acc[mi][2 + ni] = __builtin_amdgcn_mfma_f32_16x16x32_bf16(
                        afr[mi][kk], bf1[ni][kk], acc[mi][2 + ni], 0, 0, 0);
        __builtin_amdgcn_s_setprio(0);
        __builtin_amdgcn_s_barrier();

        // ---------- phase 2: quadrant (1,0); stage B-half0(t+1)
#pragma unroll
        for (int mi = 0; mi < 4; mi++)
#pragma unroll
            for (int kk = 0; kk < 2; kk++)
                afr[mi][kk] = ldA(b, wm * 128 + 64 + mi * 16, kk);
        if (st) stage(ts, sb, 0, false);
        __builtin_amdgcn_s_barrier();
        asm volatile("s_waitcnt lgkmcnt(0)" ::: "memory");
        __builtin_amdgcn_s_setprio(1);
#pragma unroll
        for (int mi = 0; mi < 4; mi++)
#pragma unroll
            for (int ni = 0; ni < 2; ni++)
#pragma unroll
                for (int kk = 0; kk < 2; kk++)
                    acc[4 + mi][ni] = __builtin_amdgcn_mfma_f32_16x16x32_bf16(
                        afr[mi][kk], bf0[ni][kk], acc[4 + mi][ni], 0, 0, 0);
        __builtin_amdgcn_s_setprio(0);
        __builtin_amdgcn_s_barrier();

        // ---------- phase 3: quadrant (1,1); stage B-half1(t+1)
        if (st) stage(ts, sb, 1, false);
        __builtin_amdgcn_s_barrier();
        __builtin_amdgcn_s_setprio(1);
#pragma unroll
        for (int mi = 0; mi < 4; mi++)
#pragma unroll
            for (int ni = 0; ni < 2; ni++)
#pragma unroll
                for (int kk = 0; kk < 2; kk++)
                    acc[4 + mi][2 + ni] = __builtin_amdgcn_mfma_f32_16x16x32_bf16(
                        afr[mi][kk], bf1[ni][kk], acc[4 + mi][2 + ni], 0, 0, 0);
        __builtin_amdgcn_s_setprio(0);
        __builtin_amdgcn_s_barrier();
    }

    if constexpr (MODE == 1) {
        const float* bv = bias + e * NDIM;
#pragma unroll
        for (int n = 0; n < 4; n++) {
            int gc = colBase + wn * 64 + n * 16 + lr;
            float bb = bv[gc];
#pragma unroll
            for (int m = 0; m < 8; m++) {
                int rl = wm * 128 + m * 16 + quad * 4;
#pragma unroll
                for (int i = 0; i < 4; i++) {
                    int r = rl + i;
                    if (r < rows) {
                        float v = fmaxf(acc[m][n][i] + bb, 0.f);
                        h[(size_t)(slotBase + r) * NDIM + gc] = f2bf(v);
                    }
                }
            }
        }
    } else {
        const float* bv = bias + e * NDIM;
#pragma unroll
        for (int m = 0; m < 8; m++) {
            int rl = wm * 128 + m * 16 + quad * 4;
#pragma unroll
            for (int i = 0; i < 4; i++) {
                int r = rl + i;
                if (r >= rows) continue;
                int s = slotBase + r;
                int tok = slot_token[s];
                float wgt = slot_weight[s];
                float* orow = out + (size_t)tok * ODIM;
#pragma unroll
                for (int n = 0; n < 4; n++) {
                    int gc = colBase + wn * 64 + n * 16 + lr;
                    float v = fmaxf(acc[m][n][i] + bv[gc], 0.f) * wgt;
                    atomicAdd(&orow[gc], v);
                }
            }
        }
    }
}

extern "C" void kernel_launch(void* const* d_in, const int* in_sizes, int n_in,
                              void* d_out, int out_size, void* d_ws, size_t ws_size,
                              hipStream_t stream) {
    const float* x  = (const float*)d_in[0];
    const float* Wg = (const float*)d_in[1];
    const float* W1 = (const float*)d_in[2];
    const float* b1 = (const float*)d_in[3];
    const float* W2 = (const float*)d_in[4];
    const float* b2 = (const float*)d_in[5];
    float* out = (float*)d_out;

    char* ws = (char*)d_ws;
    int*    counts      = (int*)(ws + 0);
    int*    offsets     = (int*)(ws + 64);
    int*    nt128       = (int*)(ws + 128);
    int*    nt256       = (int*)(ws + 132);
    int4*   t128        = (int4*)(ws + 256);
    int4*   t256        = (int4*)(ws + 2048);
    int2*   sel         = (int2*)(ws + 4096);
    float2* wts         = (float2*)(ws + 36864);
    int*    slot_token  = (int*)(ws + 69632);
    float*  slot_weight = (float*)(ws + 102400);
    unsigned short* xb  = (unsigned short*)(ws + 2097152);   //  8 MiB [NTOK][D]
    unsigned short* W1T = (unsigned short*)(ws + 10485760);  // 64 MiB [E][H][D]
    unsigned short* W2T = (unsigned short*)(ws + 77594624);  // 64 MiB [E][O][H]
    unsigned short* hbf = (unsigned short*)(ws + 144703488); // 64 MiB [NSLOT][H]

    hipMemsetAsync(d_out, 0, (size_t)NTOK * ODIM * sizeof(float), stream);
    hipMemsetAsync(ws, 0, 256, stream);

    gate_kernel<<<NTOK / 4, 256, 0, stream>>>(x, Wg, sel, wts, counts, xb);
    route_kernel<<<1, 512, 0, stream>>>(sel, wts, counts, offsets, t128, nt128, t256, nt256,
                                        slot_token, slot_weight);

    transpose_cast_kernel<<<dim3(HDIM / 64, DDIM / 64, NEXP), 256, 0, stream>>>(W1, W1T, DDIM, HDIM);
    transpose_cast_kernel<<<dim3(ODIM / 64, HDIM / 64, NEXP), 256, 0, stream>>>(W2, W2T, HDIM, ODIM);

    // GEMM1: 256x256 8-phase; colblock<->XCD affinity (16 % 8 == 0)
    moe_gemm8_kernel<1, DDIM, HDIM><<<dim3(HDIM / 256, MAXT256), 512, 0, stream>>>(
        xb, W1T, b1, t256, nt256, slot_token, slot_weight, hbf, nullptr);
    // GEMM2: 256x256 8-phase; only 4 colblocks (N=1024) -> ~144 useful blocks
    moe_gemm8_kernel<2, HDIM, ODIM><<<dim3(ODIM / 256, MAXT256), 512, 0, stream>>>(
        hbf, W2T, b2, t256, nt256, slot_token, slot_weight, nullptr, out);
}

// Round 2
// 723.475 us; speedup vs baseline: 1.0701x; 1.0701x over previous
//
#include <hip/hip_runtime.h>
#include <cstdint>

#define NTOK 4096
#define DDIM 1024
#define HDIM 4096
#define ODIM 1024
#define NEXP 8
#define NSLOT (2*NTOK)
#define MAXT128 72
#define MAXT256 40

typedef __bf16 bf16x8 __attribute__((ext_vector_type(8)));
typedef float  f32x4  __attribute__((ext_vector_type(4)));
typedef unsigned short ushort8v __attribute__((ext_vector_type(8)));

__device__ __forceinline__ unsigned short f2bf(float f) {
    union { float f; unsigned int u; } v; v.f = f;
    unsigned int r = (v.u + 0x7FFF + ((v.u >> 16) & 1)) >> 16;
    return (unsigned short)r;
}

typedef const void __attribute__((address_space(1)))* gas_ptr;
typedef void       __attribute__((address_space(3)))* las_ptr;

// ---- gate: logits = relu(x@Wg), top-2 (lowest-index tie-break), fused x->bf16 cast ----
__global__ void gate_kernel(const float* __restrict__ x, const float* __restrict__ Wg,
                            int2* __restrict__ sel, float2* __restrict__ wts,
                            int* __restrict__ counts, unsigned short* __restrict__ xb) {
    int wave = threadIdx.x >> 6;
    int lane = threadIdx.x & 63;
    int n = blockIdx.x * 4 + wave;
    float acc[NEXP];
#pragma unroll
    for (int e = 0; e < NEXP; e++) acc[e] = 0.f;
    const float* xr = x + (size_t)n * DDIM;
    unsigned short* xbr = xb + (size_t)n * DDIM;
#pragma unroll
    for (int i = 0; i < 4; i++) {
        int d = i * 256 + lane * 4;
        float4 xv = *(const float4*)&xr[d];
        ushort4 o;
        o.x = f2bf(xv.x); o.y = f2bf(xv.y); o.z = f2bf(xv.z); o.w = f2bf(xv.w);
        *(ushort4*)&xbr[d] = o;
        const float* wr = Wg + (size_t)d * NEXP;
#pragma unroll
        for (int jj = 0; jj < 4; jj++) {
            float xs = (jj == 0) ? xv.x : (jj == 1) ? xv.y : (jj == 2) ? xv.z : xv.w;
#pragma unroll
            for (int e = 0; e < NEXP; e++)
                acc[e] = fmaf(xs, wr[jj * NEXP + e], acc[e]);
        }
    }
#pragma unroll
    for (int e = 0; e < NEXP; e++) {
#pragma unroll
        for (int off = 32; off >= 1; off >>= 1)
            acc[e] += __shfl_xor(acc[e], off, 64);
    }
    if (lane == 0) {
        float l0 = -1e30f, l1 = -1e30f; int e0 = 0, e1 = 0;
#pragma unroll
        for (int e = 0; e < NEXP; e++) {
            float v = fmaxf(acc[e], 0.f);     // relu before softmax
            if (v > l0)      { l1 = l0; e1 = e0; l0 = v; e0 = e; }
            else if (v > l1) { l1 = v;  e1 = e; }
        }
        float w0 = 1.f / (1.f + expf(l1 - l0));   // softmax Z cancels in top-2 renorm
        sel[n] = make_int2(e0, e1);
        wts[n] = make_float2(w0, 1.f - w0);
        atomicAdd(&counts[e0], 1);
        atomicAdd(&counts[e1], 1);
    }
}

// ---- route: scan counts -> offsets + 128-tile and 256-tile tables, slot assignment ----
__global__ void route_kernel(const int2* __restrict__ sel, const float2* __restrict__ wts,
                             const int* __restrict__ counts, int* __restrict__ offsets,
                             int4* __restrict__ t128, int* __restrict__ nt128,
                             int4* __restrict__ t256, int* __restrict__ nt256,
                             int* __restrict__ slot_token, float* __restrict__ slot_weight) {
    __shared__ int cur[NEXP];
    int t = threadIdx.x;
    if (t == 0) {
        int s = 0, n1 = 0, n2 = 0;
        for (int e = 0; e < NEXP; e++) {
            offsets[e] = s; cur[e] = s;
            int c = counts[e];
            for (int r = 0; r < c; r += 128)
                t128[n1++] = make_int4(e, s + r, min(128, c - r), 0);
            for (int r = 0; r < c; r += 256)
                t256[n2++] = make_int4(e, s + r, min(256, c - r), 0);
            s += c;
        }
        offsets[NEXP] = s;
        *nt128 = n1; *nt256 = n2;
    }
    __syncthreads();
    for (int n = t; n < NTOK; n += blockDim.x) {
        int2 se = sel[n]; float2 w = wts[n];
        int p0 = atomicAdd(&cur[se.x], 1);
        slot_token[p0] = n; slot_weight[p0] = w.x;
        int p1 = atomicAdd(&cur[se.y], 1);
        slot_token[p1] = n; slot_weight[p1] = w.y;
    }
}

// ---- transpose+cast: src [R][C] fp32 -> dst [C][R] bf16, per expert (z) ----
__global__ void transpose_cast_kernel(const float* __restrict__ src, unsigned short* __restrict__ dst,
                                      int R, int C) {
    __shared__ float tile[64][65];
    int e = blockIdx.z;
    const float* s = src + (size_t)e * R * C;
    unsigned short* d = dst + (size_t)e * R * C;
    int t = threadIdx.x;                      // 256 threads
    int r0 = blockIdx.y * 64, c0 = blockIdx.x * 64;
#pragma unroll
    for (int p = 0; p < 4; p++) {
        int r = p * 16 + (t >> 4);
        int c = (t & 15) * 4;
        float4 v = *(const float4*)&s[(size_t)(r0 + r) * C + (c0 + c)];
        tile[r][c] = v.x; tile[r][c + 1] = v.y; tile[r][c + 2] = v.z; tile[r][c + 3] = v.w;
    }
    __syncthreads();
    int c = t >> 2, rb = (t & 3) * 16;
#pragma unroll
    for (int j = 0; j < 2; j++) {
        ushort8v v;
#pragma unroll
        for (int i = 0; i < 8; i++) v[i] = f2bf(tile[rb + j * 8 + i][c]);
        *(ushort8v*)&d[(size_t)(c0 + c) * R + (r0 + rb + j * 8)] = v;
    }
}

// ---- depth-2 pipelined MFMA GEMM: 128xTN tile, BK=32, 3-stage circular LDS ----
// 256 thr = 4 waves (WM x WN). Per K-tile: stage(t+2) -> vmcnt(2L) [t landed, t+1 &
// t+2 in flight] -> barrier -> ds_read frags -> lgkmcnt(0) -> barrier -> MFMA.
// MFMA is outside the barrier critical path; loads stay in flight across barriers.
// LDS swizzle (proven 0-conflict): slot(r,u) = u ^ ((r>>1)&3) on 16B units of 64B rows;
// inverse folded into per-lane global source address (global_load_lds dest is linear).
// Grid swizzle: chunked-bijective XCD map over ordering o=(tg*NCOL+col)*8+ti so each
// XCD runs ~8 tiles x 8 colblocks concurrently -> K-slices hit L2 (8x reuse A and B).
// MODE 1: A gathered via slot_token; epi: +b1, relu, bf16 -> h
// MODE 2: A = h slots;               epi: +b2, relu, *wgt, atomicAdd out
template <int MODE, int KDIM, int NDIM, int TN, int WN, int MINW, int NCOL>
__global__ __launch_bounds__(256, MINW) void moe_gemm_kernel(
    const unsigned short* __restrict__ A,
    const unsigned short* __restrict__ B,
    const float* __restrict__ bias,
    const int4* __restrict__ tile_meta,
    const int* __restrict__ ntiles,
    const int* __restrict__ slot_token,
    const float* __restrict__ slot_weight,
    unsigned short* __restrict__ h,
    float* __restrict__ out) {

    constexpr int WM = 4 / WN;           // wave grid WM x WN
    constexpr int FM = 128 / WM / 16;    // A frags per wave
    constexpr int FN = TN / WN / 16;     // B frags per wave
    constexpr int NT = KDIM / 32;        // K-tiles
    constexpr int LB = TN / 64;          // B loads / thread / stage
    // loads per thread per stage L = 2 + LB; vmcnt thresholds 2L / L / 0

    // ---- chunked XCD swizzle: hw id -> order o; decode (tilegroup, col, tile)
    constexpr int nwg = NCOL * MAXT128;  // grid is x=NCOL, y=MAXT128; nwg % 8 == 0
    int bid = blockIdx.y * NCOL + blockIdx.x;
    int o = (bid & 7) * (nwg >> 3) + (bid >> 3);
    int tg = o / (8 * NCOL);
    int rem = o - tg * (8 * NCOL);
    int col = rem >> 3;
    int tile = tg * 8 + (rem & 7);
    if (tile >= *ntiles) return;
    int colBase = col * TN;

    int4 tm = tile_meta[tile];
    int e = tm.x, slotBase = tm.y, rows = tm.z;

    __shared__ __align__(16) unsigned short As[3][128 * 32];
    __shared__ __align__(16) unsigned short Bs[3][TN * 32];

    int tid = threadIdx.x;
    int w = tid >> 6, lane = tid & 63;
    int quad = lane >> 4, lr = lane & 15;
    int wm = w / WN, wn = w % WN;

    const unsigned short* Be = B + (size_t)e * NDIM * KDIM;

    // staging: thread covers rows (tid>>2)+i*64; global 16B-unit g = inverse swizzle
    int srow = tid >> 2;
    int g = (tid & 3) ^ ((tid >> 3) & 3);
    unsigned int aoff[2];
    unsigned int boff[LB];
#pragma unroll
    for (int i = 0; i < 2; i++) {
        int r = srow + i * 64;
        int slot = min(slotBase + r, NSLOT - 1);
        if constexpr (MODE == 1) aoff[i] = (unsigned)(slot_token[slot] * KDIM + g * 8);
        else                     aoff[i] = (unsigned)(slot * KDIM + g * 8);
    }
#pragma unroll
    for (int i = 0; i < LB; i++)
        boff[i] = (unsigned)((colBase + srow + i * 64) * KDIM + g * 8);

    auto stage = [&](int t, int sbuf) {
        char* Ab = (char*)&As[sbuf][0] + (size_t)(w * 64) * 16;
        char* Bb = (char*)&Bs[sbuf][0] + (size_t)(w * 64) * 16;
#pragma unroll
        for (int i = 0; i < 2; i++)
            __builtin_amdgcn_global_load_lds((gas_ptr)(A + aoff[i] + t * 32),
                                             (las_ptr)(Ab + i * 4096), 16, 0, 0);
#pragma unroll
        for (int i = 0; i < LB; i++)
            __builtin_amdgcn_global_load_lds((gas_ptr)(Be + boff[i] + t * 32),
                                             (las_ptr)(Bb + i * 4096), 16, 0, 0);
    };

    auto ldfrag = [&](const unsigned short* base, int R) -> bf16x8 {
        int s = quad ^ ((R >> 1) & 3);
        return *(const bf16x8*)((const char*)base + R * 64 + s * 16);
    };

    f32x4 zero = {0.f, 0.f, 0.f, 0.f};
    f32x4 acc[FM][FN];
#pragma unroll
    for (int m = 0; m < FM; m++)
#pragma unroll
        for (int n = 0; n < FN; n++) acc[m][n] = zero;

    stage(0, 0);
    stage(1, 1);
    int sb = 2, rb = 0;
    for (int t = 0; t < NT; ++t) {
        if (t + 2 < NT) {
            stage(t + 2, sb);
            if constexpr (LB == 4) asm volatile("s_waitcnt vmcnt(12)" ::: "memory");
            else                   asm volatile("s_waitcnt vmcnt(8)" ::: "memory");
        } else if (t + 1 < NT) {
            if constexpr (LB == 4) asm volatile("s_waitcnt vmcnt(6)" ::: "memory");
            else                   asm volatile("s_waitcnt vmcnt(4)" ::: "memory");
        } else {
            asm volatile("s_waitcnt vmcnt(0)" ::: "memory");
        }
        __builtin_amdgcn_s_barrier();      // tile t fully landed (all waves)

        bf16x8 af[FM], bf[FN];
        const unsigned short* Ar = As[rb];
        const unsigned short* Br = Bs[rb];
#pragma unroll
        for (int m = 0; m < FM; m++) af[m] = ldfrag(Ar, wm * (128 / WM) + m * 16 + lr);
#pragma unroll
        for (int n = 0; n < FN; n++) bf[n] = ldfrag(Br, wn * (TN / WN) + n * 16 + lr);
        asm volatile("s_waitcnt lgkmcnt(0)" ::: "memory");
        __builtin_amdgcn_s_barrier();      // all reads done -> buffer reusable next iter

        __builtin_amdgcn_s_setprio(1);
#pragma unroll
        for (int m = 0; m < FM; m++)
#pragma unroll
            for (int n = 0; n < FN; n++)
                acc[m][n] = __builtin_amdgcn_mfma_f32_16x16x32_bf16(af[m], bf[n], acc[m][n], 0, 0, 0);
        __builtin_amdgcn_s_setprio(0);

        sb = (sb == 2) ? 0 : sb + 1;
        rb = (rb == 2) ? 0 : rb + 1;
    }

    if constexpr (MODE == 1) {
        const float* bv = bias + e * NDIM;
#pragma unroll
        for (int n = 0; n < FN; n++) {
            int gc = colBase + wn * (TN / WN) + n * 16 + lr;
            float bb = bv[gc];
#pragma unroll
            for (int m = 0; m < FM; m++) {
                int rl = wm * (128 / WM) + m * 16 + quad * 4;
#pragma unroll
                for (int i = 0; i < 4; i++) {
                    int r = rl + i;
                    if (r < rows) {
                        float v = fmaxf(acc[m][n][i] + bb, 0.f);
                        h[(size_t)(slotBase + r) * NDIM + gc] = f2bf(v);
                    }
                }
            }
        }
    } else {
        const float* bv = bias + e * NDIM;
#pragma unroll
        for (int m = 0; m < FM; m++) {
            int rl = wm * (128 / WM) + m * 16 + quad * 4;
#pragma unroll
            for (int i = 0; i < 4; i++) {
                int r = rl + i;
                if (r >= rows) continue;
                int s = slotBase + r;
                int tok = slot_token[s];
                float wgt = slot_weight[s];
                float* orow = out + (size_t)tok * ODIM;
#pragma unroll
                for (int n = 0; n < FN; n++) {
                    int gc = colBase + wn * (TN / WN) + n * 16 + lr;
                    float v = fmaxf(acc[m][n][i] + bv[gc], 0.f) * wgt;
                    atomicAdd(&orow[gc], v);
                }
            }
        }
    }
}

extern "C" void kernel_launch(void* const* d_in, const int* in_sizes, int n_in,
                              void* d_out, int out_size, void* d_ws, size_t ws_size,
                              hipStream_t stream) {
    const float* x  = (const float*)d_in[0];
    const float* Wg = (const float*)d_in[1];
    const float* W1 = (const float*)d_in[2];
    const float* b1 = (const float*)d_in[3];
    const float* W2 = (const float*)d_in[4];
    const float* b2 = (const float*)d_in[5];
    float* out = (float*)d_out;

    char* ws = (char*)d_ws;
    int*    counts      = (int*)(ws + 0);
    int*    offsets     = (int*)(ws + 64);
    int*    nt128       = (int*)(ws + 128);
    int*    nt256       = (int*)(ws + 132);
    int4*   t128        = (int4*)(ws + 256);
    int4*   t256        = (int4*)(ws + 2048);
    int2*   sel         = (int2*)(ws + 4096);
    float2* wts         = (float2*)(ws + 36864);
    int*    slot_token  = (int*)(ws + 69632);
    float*  slot_weight = (float*)(ws + 102400);
    unsigned short* xb  = (unsigned short*)(ws + 2097152);   //  8 MiB [NTOK][D]
    unsigned short* W1T = (unsigned short*)(ws + 10485760);  // 64 MiB [E][H][D]
    unsigned short* W2T = (unsigned short*)(ws + 77594624);  // 64 MiB [E][O][H]
    unsigned short* hbf = (unsigned short*)(ws + 144703488); // 64 MiB [NSLOT][H]

    hipMemsetAsync(d_out, 0, (size_t)NTOK * ODIM * sizeof(float), stream);
    hipMemsetAsync(ws, 0, 256, stream);

    gate_kernel<<<NTOK / 4, 256, 0, stream>>>(x, Wg, sel, wts, counts, xb);
    route_kernel<<<1, 512, 0, stream>>>(sel, wts, counts, offsets, t128, nt128, t256, nt256,
                                        slot_token, slot_weight);

    transpose_cast_kernel<<<dim3(HDIM / 64, DDIM / 64, NEXP), 256, 0, stream>>>(W1, W1T, DDIM, HDIM);
    transpose_cast_kernel<<<dim3(ODIM / 64, HDIM / 64, NEXP), 256, 0, stream>>>(W2, W2T, HDIM, ODIM);

    // GEMM1: 128x256, depth-2, 2 blocks/CU, 1152 blocks, XCD-grouped 8 tiles x 8 cols
    moe_gemm_kernel<1, DDIM, HDIM, 256, 4, 2, 16><<<dim3(16, MAXT128), 256, 0, stream>>>(
        xb, W1T, b1, t128, nt128, slot_token, slot_weight, hbf, nullptr);
    // GEMM2: 128x128, depth-2, 3 blocks/CU, 576 blocks, XCD-grouped 8 tiles x 8 cols
    moe_gemm_kernel<2, HDIM, ODIM, 128, 2, 3, 8><<<dim3(8, MAXT128), 256, 0, stream>>>(
        hbf, W2T, b2, t128, nt128, slot_token, slot_weight, nullptr, out);
}

// Round 3
// 715.719 us; speedup vs baseline: 1.0817x; 1.0108x over previous
//
#include <hip/hip_runtime.h>
#include <cstdint>

#define NTOK 4096
#define DDIM 1024
#define HDIM 4096
#define ODIM 1024
#define NEXP 8
#define NSLOT (2*NTOK)
#define MAXT128 72

typedef __bf16 bf16x8 __attribute__((ext_vector_type(8)));
typedef float  f32x4  __attribute__((ext_vector_type(4)));
typedef unsigned short ushort8v __attribute__((ext_vector_type(8)));

__device__ __forceinline__ unsigned short f2bf(float f) {
    union { float f; unsigned int u; } v; v.f = f;
    unsigned int r = (v.u + 0x7FFF + ((v.u >> 16) & 1)) >> 16;
    return (unsigned short)r;
}

typedef const void __attribute__((address_space(1)))* gas_ptr;
typedef void       __attribute__((address_space(3)))* las_ptr;

template <int N> __device__ __forceinline__ void vm_wait() {
    if constexpr (N == 0) asm volatile("s_waitcnt vmcnt(0)" ::: "memory");
    else if constexpr (N == 3) asm volatile("s_waitcnt vmcnt(3)" ::: "memory");
    else if constexpr (N == 4) asm volatile("s_waitcnt vmcnt(4)" ::: "memory");
    else if constexpr (N == 6) asm volatile("s_waitcnt vmcnt(6)" ::: "memory");
}

// ---- gate: logits = relu(x@Wg), top-2 (lowest-index tie-break), fused x->bf16 cast ----
__global__ void gate_kernel(const float* __restrict__ x, const float* __restrict__ Wg,
                            int2* __restrict__ sel, float2* __restrict__ wts,
                            int* __restrict__ counts, unsigned short* __restrict__ xb) {
    int wave = threadIdx.x >> 6;
    int lane = threadIdx.x & 63;
    int n = blockIdx.x * 4 + wave;
    float acc[NEXP];
#pragma unroll
    for (int e = 0; e < NEXP; e++) acc[e] = 0.f;
    const float* xr = x + (size_t)n * DDIM;
    unsigned short* xbr = xb + (size_t)n * DDIM;
#pragma unroll
    for (int i = 0; i < 4; i++) {
        int d = i * 256 + lane * 4;
        float4 xv = *(const float4*)&xr[d];
        ushort4 o;
        o.x = f2bf(xv.x); o.y = f2bf(xv.y); o.z = f2bf(xv.z); o.w = f2bf(xv.w);
        *(ushort4*)&xbr[d] = o;
        const float* wr = Wg + (size_t)d * NEXP;
#pragma unroll
        for (int jj = 0; jj < 4; jj++) {
            float xs = (jj == 0) ? xv.x : (jj == 1) ? xv.y : (jj == 2) ? xv.z : xv.w;
#pragma unroll
            for (int e = 0; e < NEXP; e++)
                acc[e] = fmaf(xs, wr[jj * NEXP + e], acc[e]);
        }
    }
#pragma unroll
    for (int e = 0; e < NEXP; e++) {
#pragma unroll
        for (int off = 32; off >= 1; off >>= 1)
            acc[e] += __shfl_xor(acc[e], off, 64);
    }
    if (lane == 0) {
        float l0 = -1e30f, l1 = -1e30f; int e0 = 0, e1 = 0;
#pragma unroll
        for (int e = 0; e < NEXP; e++) {
            float v = fmaxf(acc[e], 0.f);     // relu before softmax
            if (v > l0)      { l1 = l0; e1 = e0; l0 = v; e0 = e; }
            else if (v > l1) { l1 = v;  e1 = e; }
        }
        float w0 = 1.f / (1.f + expf(l1 - l0));   // softmax Z cancels in top-2 renorm
        sel[n] = make_int2(e0, e1);
        wts[n] = make_float2(w0, 1.f - w0);
        atomicAdd(&counts[e0], 1);
        atomicAdd(&counts[e1], 1);
    }
}

// ---- route: scan counts -> offsets + 128-tile table, slot assignment + token->slot map ----
__global__ void route_kernel(const int2* __restrict__ sel, const float2* __restrict__ wts,
                             const int* __restrict__ counts, int* __restrict__ offsets,
                             int4* __restrict__ t128, int* __restrict__ nt128,
                             int* __restrict__ slot_token, float* __restrict__ slot_weight,
                             int2* __restrict__ tokslot) {
    __shared__ int cur[NEXP];
    int t = threadIdx.x;
    if (t == 0) {
        int s = 0, n1 = 0;
        for (int e = 0; e < NEXP; e++) {
            offsets[e] = s; cur[e] = s;
            int c = counts[e];
            for (int r = 0; r < c; r += 128)
                t128[n1++] = make_int4(e, s + r, min(128, c - r), 0);
            s += c;
        }
        offsets[NEXP] = s;
        *nt128 = n1;
    }
    __syncthreads();
    for (int n = t; n < NTOK; n += blockDim.x) {
        int2 se = sel[n]; float2 w = wts[n];
        int p0 = atomicAdd(&cur[se.x], 1);
        slot_token[p0] = n; slot_weight[p0] = w.x;
        int p1 = atomicAdd(&cur[se.y], 1);
        slot_token[p1] = n; slot_weight[p1] = w.y;
        tokslot[n] = make_int2(p0, p1);
    }
}

// ---- transpose+cast: src [R][C] fp32 -> dst [C][R] bf16, per expert (z) ----
__global__ void transpose_cast_kernel(const float* __restrict__ src, unsigned short* __restrict__ dst,
                                      int R, int C) {
    __shared__ float tile[64][65];
    int e = blockIdx.z;
    const float* s = src + (size_t)e * R * C;
    unsigned short* d = dst + (size_t)e * R * C;
    int t = threadIdx.x;                      // 256 threads
    int r0 = blockIdx.y * 64, c0 = blockIdx.x * 64;
#pragma unroll
    for (int p = 0; p < 4; p++) {
        int r = p * 16 + (t >> 4);
        int c = (t & 15) * 4;
        float4 v = *(const float4*)&s[(size_t)(r0 + r) * C + (c0 + c)];
        tile[r][c] = v.x; tile[r][c + 1] = v.y; tile[r][c + 2] = v.z; tile[r][c + 3] = v.w;
    }
    __syncthreads();
    int c = t >> 2, rb = (t & 3) * 16;
#pragma unroll
    for (int j = 0; j < 2; j++) {
        ushort8v v;
#pragma unroll
        for (int i = 0; i < 8; i++) v[i] = f2bf(tile[rb + j * 8 + i][c]);
        *(ushort8v*)&d[(size_t)(c0 + c) * R + (r0 + rb + j * 8)] = v;
    }
}

// ---- reg-frag double-buffered MFMA GEMM: 128xTN tile, BK=32, 3-stage circular LDS ----
// Per K-tile t: stage(t+2) -> vmcnt(L) [t+1 landed] -> barrier -> issue ds_read of
// frags(t+1) into the OTHER named frag set -> MFMA(frags(t)) OVERLAPS the reads ->
// lgkmcnt(0)+sched_barrier -> barrier. Loop unrolled x2 (named fragsA/fragsB; rule #20).
// SWAPPED MFMA operands: mfma(bf, af) -> lane holds 4 consecutive OUTPUT COLUMNS
// (row = m*16+lr, cols = n*16+quad*4 .. +3) -> packed vector epilogue stores.
// LDS swizzle (0-conflict proven): slot(r,u) = u ^ ((r>>1)&3) on 16B units; inverse
// folded into per-lane global source addr (global_load_lds dest is linear).
// Grid swizzle: chunked-bijective XCD map, 8 tiles x 8 cols per XCD -> L2 reuse.
// MODE 1: A gathered via slot_token; epi: +b1, relu, bf16 dwordx2 -> h
// MODE 2: A = h slots; epi: +b2, relu, f32 dwordx4 -> y (unweighted; combine later)
template <int MODE, int KDIM, int NDIM, int THREADS, int TN, int WM, int WN, int MINW, int NCOL>
__global__ __launch_bounds__(THREADS, MINW) void moe_gemm_kernel(
    const unsigned short* __restrict__ A,
    const unsigned short* __restrict__ B,
    const float* __restrict__ bias,
    const int4* __restrict__ tile_meta,
    const int* __restrict__ ntiles,
    const int* __restrict__ slot_token,
    unsigned short* __restrict__ h,
    float* __restrict__ yout) {

    constexpr int TM = 128;
    constexpr int RM = TM / WM, RN = TN / WN;
    constexpr int FM = RM / 16, FN = RN / 16;
    constexpr int NT = KDIM / 32;            // K-tiles (even for all our cases)
    constexpr int LA = TM * 4 / THREADS;     // A 16B-units per thread per K-step
    constexpr int LB = TN * 4 / THREADS;
    constexpr int L  = LA + LB;

    // ---- chunked XCD swizzle: hw id -> order o; decode (tilegroup, col, tile)
    constexpr int nwg = NCOL * MAXT128;      // % 8 == 0
    int bid = blockIdx.y * NCOL + blockIdx.x;
    int o = (bid & 7) * (nwg >> 3) + (bid >> 3);
    int tg = o / (8 * NCOL);
    int rem = o - tg * (8 * NCOL);
    int col = rem >> 3;
    int tile = tg * 8 + (rem & 7);
    if (tile >= *ntiles) return;
    int colBase = col * TN;

    int4 tm = tile_meta[tile];
    int e = tm.x, slotBase = tm.y, rows = tm.z;

    __shared__ __align__(16) unsigned short As[3][TM * 32];
    __shared__ __align__(16) unsigned short Bs[3][TN * 32];

    int tid = threadIdx.x;
    int w = tid >> 6, lane = tid & 63;
    int quad = lane >> 4, lr = lane & 15;
    int wm = w / WN, wn = w % WN;

    const unsigned short* Be = B + (size_t)e * NDIM * KDIM;

    // staging: 16B unit u = i*THREADS+tid covers row u>>2, swizzled global unit g
    unsigned int aoff[LA];
    unsigned int boff[LB];
#pragma unroll
    for (int i = 0; i < LA; i++) {
        int u = i * THREADS + tid;
        int r = u >> 2, g = (u & 3) ^ ((u >> 3) & 3);
        int slot = min(slotBase + r, NSLOT - 1);
        if constexpr (MODE == 1) aoff[i] = (unsigned)(slot_token[slot] * KDIM + g * 8);
        else                     aoff[i] = (unsigned)(slot * KDIM + g * 8);
    }
#pragma unroll
    for (int i = 0; i < LB; i++) {
        int u = i * THREADS + tid;
        int r = u >> 2, g = (u & 3) ^ ((u >> 3) & 3);
        boff[i] = (unsigned)((colBase + r) * KDIM + g * 8);
    }

    auto stage = [&](int t, int sbuf) {
        char* Ab = (char*)&As[sbuf][0] + w * 1024;   // wave-uniform base; HW adds lane*16
        char* Bb = (char*)&Bs[sbuf][0] + w * 1024;
#pragma unroll
        for (int i = 0; i < LA; i++)
            __builtin_amdgcn_global_load_lds((gas_ptr)(A + aoff[i] + t * 32),
                                             (las_ptr)(Ab + i * THREADS * 16), 16, 0, 0);
#pragma unroll
        for (int i = 0; i < LB; i++)
            __builtin_amdgcn_global_load_lds((gas_ptr)(Be + boff[i] + t * 32),
                                             (las_ptr)(Bb + i * THREADS * 16), 16, 0, 0);
    };

    auto rdfrags = [&](bf16x8 (&af)[FM], bf16x8 (&bf)[FN], int buf) {
        const char* Ar = (const char*)&As[buf][0];
        const char* Br = (const char*)&Bs[buf][0];
#pragma unroll
        for (int m = 0; m < FM; m++) {
            int R = wm * RM + m * 16 + lr;
            int s = quad ^ ((R >> 1) & 3);
            af[m] = *(const bf16x8*)(Ar + R * 64 + s * 16);
        }
#pragma unroll
        for (int n = 0; n < FN; n++) {
            int R = wn * RN + n * 16 + lr;
            int s = quad ^ ((R >> 1) & 3);
            bf[n] = *(const bf16x8*)(Br + R * 64 + s * 16);
        }
    };

    f32x4 zero = {0.f, 0.f, 0.f, 0.f};
    f32x4 acc[FM][FN];
#pragma unroll
    for (int m = 0; m < FM; m++)
#pragma unroll
        for (int n = 0; n < FN; n++) acc[m][n] = zero;

    auto mfma_all = [&](bf16x8 (&af)[FM], bf16x8 (&bf)[FN]) {
        __builtin_amdgcn_s_setprio(1);
#pragma unroll
        for (int m = 0; m < FM; m++)
#pragma unroll
            for (int n = 0; n < FN; n++)   // SWAPPED operands -> transposed lane layout
                acc[m][n] = __builtin_amdgcn_mfma_f32_16x16x32_bf16(bf[n], af[m], acc[m][n], 0, 0, 0);
        __builtin_amdgcn_s_setprio(0);
    };

    bf16x8 afA[FM], bfA[FN], afB[FM], bfB[FN];

    // prologue: stage tiles 0,1; read frags(0) into set A
    stage(0, 0);
    stage(1, 1);
    vm_wait<L>();
    __builtin_amdgcn_s_barrier();
    rdfrags(afA, bfA, 0);
    asm volatile("s_waitcnt lgkmcnt(0)" ::: "memory");
    __builtin_amdgcn_sched_barrier(0);

    int sb = 2, rb = 1;
    for (int t = 0; t < NT; t += 2) {
        // ---- even body: MFMA(set A, tile t); read set B <- tile t+1; stage t+2
        bool st2 = (t + 2 < NT);
        if (st2) stage(t + 2, sb);
        if (st2) vm_wait<L>(); else vm_wait<0>();
        __builtin_amdgcn_s_barrier();
        rdfrags(afB, bfB, rb);
        mfma_all(afA, bfA);
        asm volatile("s_waitcnt lgkmcnt(0)" ::: "memory");
        __builtin_amdgcn_sched_barrier(0);
        __builtin_amdgcn_s_barrier();
        sb = (sb == 2) ? 0 : sb + 1;
        rb = (rb == 2) ? 0 : rb + 1;

        // ---- odd body: MFMA(set B, tile t+1); read set A <- tile t+2; stage t+3
        bool st3 = (t + 3 < NT);
        if (st3) stage(t + 3, sb);
        if (st2) { if (st3) vm_wait<L>(); else vm_wait<0>(); }
        __builtin_amdgcn_s_barrier();
        if (st2) rdfrags(afA, bfA, rb);
        mfma_all(afB, bfB);
        asm volatile("s_waitcnt lgkmcnt(0)" ::: "memory");
        __builtin_amdgcn_sched_barrier(0);
        __builtin_amdgcn_s_barrier();
        sb = (sb == 2) ? 0 : sb + 1;
        rb = (rb == 2) ? 0 : rb + 1;
    }

    // ---- epilogue (swapped layout: row = m*16+lr, cols = n*16+quad*4 .. +3)
    const float* bv = bias + e * NDIM;
    if constexpr (MODE == 1) {
#pragma unroll
        for (int m = 0; m < FM; m++) {
            int r = wm * RM + m * 16 + lr;
            if (r < rows) {
                unsigned short* hrow = h + (size_t)(slotBase + r) * NDIM;
#pragma unroll
                for (int n = 0; n < FN; n++) {
                    int c = colBase + wn * RN + n * 16 + quad * 4;
                    float4 bb = *(const float4*)&bv[c];
                    unsigned int lo = (unsigned)f2bf(fmaxf(acc[m][n][0] + bb.x, 0.f)) |
                                      ((unsigned)f2bf(fmaxf(acc[m][n][1] + bb.y, 0.f)) << 16);
                    unsigned int hi = (unsigned)f2bf(fmaxf(acc[m][n][2] + bb.z, 0.f)) |
                                      ((unsigned)f2bf(fmaxf(acc[m][n][3] + bb.w, 0.f)) << 16);
                    uint2 pv = make_uint2(lo, hi);
                    *(uint2*)&hrow[c] = pv;
                }
            }
        }
    } else {
#pragma unroll
        for (int m = 0; m < FM; m++) {
            int r = wm * RM + m * 16 + lr;
            if (r < rows) {
                float* yrow = yout + (size_t)(slotBase + r) * NDIM;
#pragma unroll
                for (int n = 0; n < FN; n++) {
                    int c = colBase + wn * RN + n * 16 + quad * 4;
                    float4 bb = *(const float4*)&bv[c];
                    float4 v;
                    v.x = fmaxf(acc[m][n][0] + bb.x, 0.f);
                    v.y = fmaxf(acc[m][n][1] + bb.y, 0.f);
                    v.z = fmaxf(acc[m][n][2] + bb.z, 0.f);
                    v.w = fmaxf(acc[m][n][3] + bb.w, 0.f);
                    *(float4*)&yrow[c] = v;
                }
            }
        }
    }
}

// ---- combine: out[n] = w0 * y[p0] + w1 * y[p1] ----
__global__ void combine_kernel(const float* __restrict__ y, const int2* __restrict__ tokslot,
                               const float2* __restrict__ wts, float* __restrict__ out) {
    int n = blockIdx.x;
    int t = threadIdx.x;
    int2 ts = tokslot[n];
    float2 w = wts[n];
    float4 a = *(const float4*)&y[(size_t)ts.x * ODIM + t * 4];
    float4 b = *(const float4*)&y[(size_t)ts.y * ODIM + t * 4];
    float4 o;
    o.x = w.x * a.x + w.y * b.x;
    o.y = w.x * a.y + w.y * b.y;
    o.z = w.x * a.z + w.y * b.z;
    o.w = w.x * a.w + w.y * b.w;
    *(float4*)&out[(size_t)n * ODIM + t * 4] = o;
}

extern "C" void kernel_launch(void* const* d_in, const int* in_sizes, int n_in,
                              void* d_out, int out_size, void* d_ws, size_t ws_size,
                              hipStream_t stream) {
    const float* x  = (const float*)d_in[0];
    const float* Wg = (const float*)d_in[1];
    const float* W1 = (const float*)d_in[2];
    const float* b1 = (const float*)d_in[3];
    const float* W2 = (const float*)d_in[4];
    const float* b2 = (const float*)d_in[5];
    float* out = (float*)d_out;

    char* ws = (char*)d_ws;
    int*    counts      = (int*)(ws + 0);
    int*    offsets     = (int*)(ws + 64);
    int*    nt128       = (int*)(ws + 128);
    int4*   t128        = (int4*)(ws + 256);
    int2*   sel         = (int2*)(ws + 4096);
    float2* wts         = (float2*)(ws + 36864);
    int*    slot_token  = (int*)(ws + 69632);
    float*  slot_weight = (float*)(ws + 102400);
    int2*   tokslot     = (int2*)(ws + 135168);
    unsigned short* xb  = (unsigned short*)(ws + 2097152);   //  8 MiB [NTOK][D]
    unsigned short* W1T = (unsigned short*)(ws + 10485760);  // 64 MiB [E][H][D]
    unsigned short* W2T = (unsigned short*)(ws + 77594624);  // 64 MiB [E][O][H]
    unsigned short* hbf = (unsigned short*)(ws + 144703488); // 64 MiB [NSLOT][H]
    float* ybf = (float*)(ws + 10485760);                    // 32 MiB [NSLOT][O], reuses dead W1T

    hipMemsetAsync(ws, 0, 256, stream);

    gate_kernel<<<NTOK / 4, 256, 0, stream>>>(x, Wg, sel, wts, counts, xb);
    route_kernel<<<1, 512, 0, stream>>>(sel, wts, counts, offsets, t128, nt128,
                                        slot_token, slot_weight, tokslot);

    transpose_cast_kernel<<<dim3(HDIM / 64, DDIM / 64, NEXP), 256, 0, stream>>>(W1, W1T, DDIM, HDIM);
    transpose_cast_kernel<<<dim3(ODIM / 64, HDIM / 64, NEXP), 256, 0, stream>>>(W2, W2T, HDIM, ODIM);

    // GEMM1: 128x256, 512 thr (2x4 waves), reg-frag dbuf, 1 blk/CU, 4 clean rounds
    moe_gemm_kernel<1, DDIM, HDIM, 512, 256, 2, 4, 2, 16><<<dim3(16, MAXT128), 512, 0, stream>>>(
        xb, W1T, b1, t128, nt128, slot_token, hbf, nullptr);
    // GEMM2: 128x128, 256 thr (2x2 waves), reg-frag dbuf, 2 blk/CU, 1 clean round
    moe_gemm_kernel<2, HDIM, ODIM, 256, 128, 2, 2, 2, 8><<<dim3(8, MAXT128), 256, 0, stream>>>(
        hbf, W2T, b2, t128, nt128, slot_token, nullptr, ybf);

    combine_kernel<<<NTOK, 256, 0, stream>>>(ybf, tokslot, wts, out);
}